// Round 1
// baseline (40.398 us; speedup 1.0000x reference)
//
#include <hip/hip_runtime.h>

// LocallyConnected2d: out[b,o,l] = sum_d patches[b,d,l] * w[d,l,o] + bias[o,l]
// B=8, C_IN=32, H=W=48, C_OUT=32, K=3 -> DEPTH=288, L=2304. All fp32.
// Memory-bound on the 85 MB weight stream (read exactly once; reuse only over B).

constexpr int NB    = 8;
constexpr int CIN   = 32;
constexpr int HWD   = 48;
constexpr int COUT  = 32;
constexpr int DEPTH = 288;   // CIN*3*3
constexpr int LTOT  = 2304;  // 48*48
constexpr int DSPLIT = 4;            // one wave per depth-chunk
constexpr int DCHUNK = DEPTH / DSPLIT; // 72
constexpr int DP    = 289;   // padded LDS stride (288 % 32 == 0 would be 8-way conflict)

__global__ __launch_bounds__(256, 6) void lc2d(const float* __restrict__ x,
                                               const float* __restrict__ wgt,
                                               const float* __restrict__ bias,
                                               float* __restrict__ out) {
    __shared__ float patches[NB * DP];        // 9248 B: patches[b*DP + d]
    __shared__ float red[DSPLIT][NB][COUT];   // 4096 B: partial sums

    const int tid = threadIdx.x;
    const int l   = blockIdx.x;          // one spatial location per block
    const int h   = l / HWD;
    const int w   = l - h * HWD;

    // ---- stage patches[b, d] for this l into LDS (8*288 = 2304 elems, 9/thread)
    #pragma unroll
    for (int it = 0; it < (NB * DEPTH) / 256; ++it) {
        const int idx = it * 256 + tid;
        const int b   = idx / DEPTH;
        const int d   = idx - b * DEPTH;
        const int c   = d / 9;           // torch-unfold order: d = c*9 + kh*3 + kw
        const int kk  = d - c * 9;
        const int kh  = kk / 3;
        const int kw  = kk - kh * 3;
        const int ih  = h + kh - 1;
        const int iw  = w + kw - 1;
        float v = 0.f;
        if ((unsigned)ih < (unsigned)HWD && (unsigned)iw < (unsigned)HWD)
            v = x[((b * CIN + c) * HWD + ih) * HWD + iw];
        patches[b * DP + d] = v;
    }
    __syncthreads();

    // ---- main loop: wave = depth chunk; lane = (b, og) with o = og*4 .. og*4+3
    const int ds   = tid >> 6;   // 0..3 depth chunk
    const int lane = tid & 63;
    const int b    = lane >> 3;  // 0..7
    const int og   = lane & 7;   // 0..7

    const float* pp = &patches[b * DP + ds * DCHUNK];
    const float* wp = wgt + ((size_t)(ds * DCHUNK) * LTOT + (size_t)l) * COUT + og * 4;

    float4 acc = make_float4(0.f, 0.f, 0.f, 0.f);
    #pragma unroll 8
    for (int i = 0; i < DCHUNK; ++i) {
        const float4 wv = *reinterpret_cast<const float4*>(wp + (size_t)i * (LTOT * COUT));
        const float  pv = pp[i];
        acc.x = fmaf(pv, wv.x, acc.x);
        acc.y = fmaf(pv, wv.y, acc.y);
        acc.z = fmaf(pv, wv.z, acc.z);
        acc.w = fmaf(pv, wv.w, acc.w);
    }

    *reinterpret_cast<float4*>(&red[ds][b][og * 4]) = acc;
    __syncthreads();

    // ---- cross-wave reduction + bias + store: thread = (b2, o2)
    const int b2 = tid >> 5;   // 0..7
    const int o2 = tid & 31;   // 0..31
    float s = red[0][b2][o2] + red[1][b2][o2] + red[2][b2][o2] + red[3][b2][o2];
    s += bias[o2 * LTOT + l];
    out[((size_t)(b2 * COUT + o2) * LTOT) + l] = s;
}

extern "C" void kernel_launch(void* const* d_in, const int* in_sizes, int n_in,
                              void* d_out, int out_size, void* d_ws, size_t ws_size,
                              hipStream_t stream) {
    const float* x    = (const float*)d_in[0];
    const float* wgt  = (const float*)d_in[1];
    const float* bias = (const float*)d_in[2];
    float* out        = (float*)d_out;
    lc2d<<<LTOT, 256, 0, stream>>>(x, wgt, bias, out);
}

// Round 2
// 37.995 us; speedup vs baseline: 1.0632x; 1.0632x over previous
//
#include <hip/hip_runtime.h>

// LocallyConnected2d: out[b,o,l] = sum_d patches[b,d,l] * w[d,l,o] + bias[o,l]
// B=8, C_IN=32, H=W=48, C_OUT=32, K=3 -> DEPTH=288, L=2304. All fp32.
// 85 MB weight read exactly once -> memory-bound. R2: maximize unique bytes
// in flight: lane=(dsub,og) so each wave-load is 1 KB unique; 9 loads fully
// unrolled per wave = 9 KB in flight/wave. b-reuse lives in registers.

constexpr int NB    = 8;
constexpr int CIN   = 32;
constexpr int HWD   = 48;
constexpr int COUT  = 32;
constexpr int DEPTH = 288;
constexpr int LTOT  = 2304;
constexpr int DSPLIT = 4;              // one wave per depth chunk
constexpr int DCHUNK = DEPTH / DSPLIT; // 72
constexpr int NIT    = DCHUNK / 8;     // 9 iterations (8 dsub lanes)
constexpr int DP     = 289;            // padded patches stride

__global__ __launch_bounds__(256, 4) void lc2d(const float* __restrict__ x,
                                               const float* __restrict__ wgt,
                                               const float* __restrict__ bias,
                                               float* __restrict__ out) {
    __shared__ float patches[NB * DP];      // 9248 B
    __shared__ float red[NB * COUT * 4];    // 4096 B: [b][o][ds]

    const int tid = threadIdx.x;
    const int l   = blockIdx.x;
    const int h   = l / HWD;
    const int w   = l - h * HWD;

    // ---- stage patches[b, d] for this l (8*288 elems, 9/thread)
    #pragma unroll
    for (int it = 0; it < (NB * DEPTH) / 256; ++it) {
        const int idx = it * 256 + tid;
        const int b   = idx / DEPTH;
        const int d   = idx - b * DEPTH;
        const int c   = d / 9;
        const int kk  = d - c * 9;
        const int kh  = kk / 3;
        const int kw  = kk - kh * 3;
        const int ih  = h + kh - 1;
        const int iw  = w + kw - 1;
        float v = 0.f;
        if ((unsigned)ih < (unsigned)HWD && (unsigned)iw < (unsigned)HWD)
            v = x[((b * CIN + c) * HWD + ih) * HWD + iw];
        patches[b * DP + d] = v;
    }
    __syncthreads();

    // ---- main: wave ds owns d in [ds*72, ds*72+72); lane=(dsub,og)
    const int ds   = tid >> 6;
    const int lane = tid & 63;
    const int dsub = lane >> 3;  // 0..7
    const int og   = lane & 7;   // 0..7
    const int d0   = ds * DCHUNK + dsub;

    const float* wp = wgt + ((size_t)d0 * LTOT + (size_t)l) * COUT + og * 4;

    // 9 independent 16B loads, all 64 lanes distinct addresses (1 KB/instr)
    float4 wv[NIT];
    #pragma unroll
    for (int i = 0; i < NIT; ++i)
        wv[i] = *reinterpret_cast<const float4*>(wp + (size_t)i * 8 * LTOT * COUT);

    float4 acc[NB];
    #pragma unroll
    for (int b = 0; b < NB; ++b) acc[b] = make_float4(0.f, 0.f, 0.f, 0.f);

    #pragma unroll
    for (int i = 0; i < NIT; ++i) {
        const int d = d0 + i * 8;
        #pragma unroll
        for (int b = 0; b < NB; ++b) {
            const float pv = patches[b * DP + d];   // 8-lane broadcast, conflict-free
            acc[b].x = fmaf(pv, wv[i].x, acc[b].x);
            acc[b].y = fmaf(pv, wv[i].y, acc[b].y);
            acc[b].z = fmaf(pv, wv[i].z, acc[b].z);
            acc[b].w = fmaf(pv, wv[i].w, acc[b].w);
        }
    }

    // ---- reduce over dsub (lane bits 3..5): xor masks 8,16,32
    #pragma unroll
    for (int m = 8; m <= 32; m <<= 1) {
        #pragma unroll
        for (int b = 0; b < NB; ++b) {
            acc[b].x += __shfl_xor(acc[b].x, m);
            acc[b].y += __shfl_xor(acc[b].y, m);
            acc[b].z += __shfl_xor(acc[b].z, m);
            acc[b].w += __shfl_xor(acc[b].w, m);
        }
    }

    if (dsub == 0) {
        #pragma unroll
        for (int b = 0; b < NB; ++b) {
            red[(b * COUT + og * 4 + 0) * 4 + ds] = acc[b].x;
            red[(b * COUT + og * 4 + 1) * 4 + ds] = acc[b].y;
            red[(b * COUT + og * 4 + 2) * 4 + ds] = acc[b].z;
            red[(b * COUT + og * 4 + 3) * 4 + ds] = acc[b].w;
        }
    }
    __syncthreads();

    // ---- combine 4 chunks + bias + store
    const int b2 = tid >> 5;   // 0..7
    const int o2 = tid & 31;   // 0..31
    const float4 r = *reinterpret_cast<const float4*>(&red[(b2 * COUT + o2) * 4]);
    float s = r.x + r.y + r.z + r.w + bias[o2 * LTOT + l];
    out[((size_t)(b2 * COUT + o2)) * LTOT + l] = s;
}

extern "C" void kernel_launch(void* const* d_in, const int* in_sizes, int n_in,
                              void* d_out, int out_size, void* d_ws, size_t ws_size,
                              hipStream_t stream) {
    const float* x    = (const float*)d_in[0];
    const float* wgt  = (const float*)d_in[1];
    const float* bias = (const float*)d_in[2];
    float* out        = (float*)d_out;
    lc2d<<<LTOT, 256, 0, stream>>>(x, wgt, bias, out);
}

// Round 3
// 29.897 us; speedup vs baseline: 1.3512x; 1.2709x over previous
//
#include <hip/hip_runtime.h>

// LocallyConnected2d: out[b,o,l] = sum_d patches[b,d,l] * w[d,l,o] + bias[o,l]
// B=8, DEPTH=288, L=2304, C_OUT=32, fp32. 85 MB weight read once (L3-resident
// across replays) -> must stream continuously, not burst-per-tiny-block.
// R3: LB=4 l's per block (grid 576, all resident), per-wave d-split (72 d),
// double-buffered weight prefetch, no main-loop barriers, float4 output.

constexpr int NB    = 8;
constexpr int CIN   = 32;
constexpr int HWD   = 48;
constexpr int COUT  = 32;
constexpr int DEPTH = 288;
constexpr int LTOT  = 2304;
constexpr int LB    = 4;                  // locations per block
constexpr int NBLK  = LTOT / LB;          // 576
constexpr int PL    = DEPTH * NB + 8;     // 2312: padded per-l stride (words)
constexpr int WSTR  = LTOT * COUT;        // 73728 floats between d-planes

__global__ __launch_bounds__(256, 3) void lc2d(const float* __restrict__ x,
                                               const float* __restrict__ wgt,
                                               const float* __restrict__ bias,
                                               float* __restrict__ out) {
    __shared__ float patches[LB * PL];              // 36,992 B: [l][d][b]
    __shared__ float red[4 * NB * LB * COUT];       // 16,384 B: [wave][b][l][o]

    const int tid = threadIdx.x;
    // XCD-chunked bijective swizzle (assumes round-robin bid->XCD): XCD k gets
    // contiguous l-tiles -> neighbor blocks share L2 lines (reads + write-merge).
    const int bid   = blockIdx.x;
    const int ltile = (bid & 7) * (NBLK / 8) + (bid >> 3);
    const int l0    = ltile * LB;
    const int h0    = l0 / HWD;               // 4 l's sit in one row (48 % 4 == 0)
    const int w0    = l0 - h0 * HWD;

    // ---- stage patches[ls][d][b]: 9216 elems, 36/thread, b fastest ----
    #pragma unroll
    for (int k = 0; k < (LB * DEPTH * NB) / 256; ++k) {
        const int sidx = k * 256 + tid;
        const int b  = sidx & 7;
        const int t2 = sidx >> 3;
        const int d  = t2 % DEPTH;
        const int ls = t2 / DEPTH;
        const int c  = d / 9;                 // torch unfold order d = c*9+kh*3+kw
        const int r9 = d - c * 9;
        const int kh = r9 / 3;
        const int kw = r9 - kh * 3;
        const int ih = h0 + kh - 1;
        const int iw = w0 + ls + kw - 1;
        float v = 0.f;
        if ((unsigned)ih < (unsigned)HWD && (unsigned)iw < (unsigned)HWD)
            v = x[((b * CIN + c) * HWD + ih) * HWD + iw];
        patches[ls * PL + d * NB + b] = v;
    }
    __syncthreads();

    // ---- main: wave owns d in [wave*72, wave*72+72); lane = (dpar,lsub,og) ----
    const int wave = tid >> 6;
    const int lane = tid & 63;
    const int og   = lane & 7;        // o = og*4 .. og*4+3
    const int lsub = (lane >> 3) & 3; // l = l0 + lsub
    const int dpar = lane >> 5;       // d half: +0 / +36
    const int d0   = wave * 72 + dpar * 36;

    const float* wp    = wgt + (size_t)d0 * WSTR + (size_t)(l0 + lsub) * COUT + og * 4;
    const float* pbase = &patches[lsub * PL + d0 * NB];

    float4 acc[NB];
    #pragma unroll
    for (int b = 0; b < NB; ++b) acc[b] = make_float4(0.f, 0.f, 0.f, 0.f);

    float4 wc[4], wn[4];
    #pragma unroll
    for (int j = 0; j < 4; ++j)
        wc[j] = *reinterpret_cast<const float4*>(wp + (size_t)j * WSTR);

    // 36 d-steps = 9 chunks of 4; prefetch chunk c+1 while computing chunk c
    for (int ch = 0; ch < 8; ++ch) {
        #pragma unroll
        for (int j = 0; j < 4; ++j)
            wn[j] = *reinterpret_cast<const float4*>(wp + (size_t)((ch + 1) * 4 + j) * WSTR);
        #pragma unroll
        for (int j = 0; j < 4; ++j) {
            const int i = ch * 4 + j;
            const float4 p0 = *reinterpret_cast<const float4*>(pbase + i * NB);
            const float4 p1 = *reinterpret_cast<const float4*>(pbase + i * NB + 4);
            acc[0].x = fmaf(p0.x, wc[j].x, acc[0].x); acc[0].y = fmaf(p0.x, wc[j].y, acc[0].y);
            acc[0].z = fmaf(p0.x, wc[j].z, acc[0].z); acc[0].w = fmaf(p0.x, wc[j].w, acc[0].w);
            acc[1].x = fmaf(p0.y, wc[j].x, acc[1].x); acc[1].y = fmaf(p0.y, wc[j].y, acc[1].y);
            acc[1].z = fmaf(p0.y, wc[j].z, acc[1].z); acc[1].w = fmaf(p0.y, wc[j].w, acc[1].w);
            acc[2].x = fmaf(p0.z, wc[j].x, acc[2].x); acc[2].y = fmaf(p0.z, wc[j].y, acc[2].y);
            acc[2].z = fmaf(p0.z, wc[j].z, acc[2].z); acc[2].w = fmaf(p0.z, wc[j].w, acc[2].w);
            acc[3].x = fmaf(p0.w, wc[j].x, acc[3].x); acc[3].y = fmaf(p0.w, wc[j].y, acc[3].y);
            acc[3].z = fmaf(p0.w, wc[j].z, acc[3].z); acc[3].w = fmaf(p0.w, wc[j].w, acc[3].w);
            acc[4].x = fmaf(p1.x, wc[j].x, acc[4].x); acc[4].y = fmaf(p1.x, wc[j].y, acc[4].y);
            acc[4].z = fmaf(p1.x, wc[j].z, acc[4].z); acc[4].w = fmaf(p1.x, wc[j].w, acc[4].w);
            acc[5].x = fmaf(p1.y, wc[j].x, acc[5].x); acc[5].y = fmaf(p1.y, wc[j].y, acc[5].y);
            acc[5].z = fmaf(p1.y, wc[j].z, acc[5].z); acc[5].w = fmaf(p1.y, wc[j].w, acc[5].w);
            acc[6].x = fmaf(p1.z, wc[j].x, acc[6].x); acc[6].y = fmaf(p1.z, wc[j].y, acc[6].y);
            acc[6].z = fmaf(p1.z, wc[j].z, acc[6].z); acc[6].w = fmaf(p1.z, wc[j].w, acc[6].w);
            acc[7].x = fmaf(p1.w, wc[j].x, acc[7].x); acc[7].y = fmaf(p1.w, wc[j].y, acc[7].y);
            acc[7].z = fmaf(p1.w, wc[j].z, acc[7].z); acc[7].w = fmaf(p1.w, wc[j].w, acc[7].w);
        }
        #pragma unroll
        for (int j = 0; j < 4; ++j) wc[j] = wn[j];
    }
    #pragma unroll
    for (int j = 0; j < 4; ++j) {           // last chunk (ch = 8)
        const int i = 32 + j;
        const float4 p0 = *reinterpret_cast<const float4*>(pbase + i * NB);
        const float4 p1 = *reinterpret_cast<const float4*>(pbase + i * NB + 4);
        acc[0].x = fmaf(p0.x, wc[j].x, acc[0].x); acc[0].y = fmaf(p0.x, wc[j].y, acc[0].y);
        acc[0].z = fmaf(p0.x, wc[j].z, acc[0].z); acc[0].w = fmaf(p0.x, wc[j].w, acc[0].w);
        acc[1].x = fmaf(p0.y, wc[j].x, acc[1].x); acc[1].y = fmaf(p0.y, wc[j].y, acc[1].y);
        acc[1].z = fmaf(p0.y, wc[j].z, acc[1].z); acc[1].w = fmaf(p0.y, wc[j].w, acc[1].w);
        acc[2].x = fmaf(p0.z, wc[j].x, acc[2].x); acc[2].y = fmaf(p0.z, wc[j].y, acc[2].y);
        acc[2].z = fmaf(p0.z, wc[j].z, acc[2].z); acc[2].w = fmaf(p0.z, wc[j].w, acc[2].w);
        acc[3].x = fmaf(p0.w, wc[j].x, acc[3].x); acc[3].y = fmaf(p0.w, wc[j].y, acc[3].y);
        acc[3].z = fmaf(p0.w, wc[j].z, acc[3].z); acc[3].w = fmaf(p0.w, wc[j].w, acc[3].w);
        acc[4].x = fmaf(p1.x, wc[j].x, acc[4].x); acc[4].y = fmaf(p1.x, wc[j].y, acc[4].y);
        acc[4].z = fmaf(p1.x, wc[j].z, acc[4].z); acc[4].w = fmaf(p1.x, wc[j].w, acc[4].w);
        acc[5].x = fmaf(p1.y, wc[j].x, acc[5].x); acc[5].y = fmaf(p1.y, wc[j].y, acc[5].y);
        acc[5].z = fmaf(p1.y, wc[j].z, acc[5].z); acc[5].w = fmaf(p1.y, wc[j].w, acc[5].w);
        acc[6].x = fmaf(p1.z, wc[j].x, acc[6].x); acc[6].y = fmaf(p1.z, wc[j].y, acc[6].y);
        acc[6].z = fmaf(p1.z, wc[j].z, acc[6].z); acc[6].w = fmaf(p1.z, wc[j].w, acc[6].w);
        acc[7].x = fmaf(p1.w, wc[j].x, acc[7].x); acc[7].y = fmaf(p1.w, wc[j].y, acc[7].y);
        acc[7].z = fmaf(p1.w, wc[j].z, acc[7].z); acc[7].w = fmaf(p1.w, wc[j].w, acc[7].w);
    }

    // ---- reduce dpar halves (lane ^ 32), then cross-wave via LDS ----
    #pragma unroll
    for (int b = 0; b < NB; ++b) {
        acc[b].x += __shfl_xor(acc[b].x, 32);
        acc[b].y += __shfl_xor(acc[b].y, 32);
        acc[b].z += __shfl_xor(acc[b].z, 32);
        acc[b].w += __shfl_xor(acc[b].w, 32);
    }
    if (lane < 32) {
        #pragma unroll
        for (int b = 0; b < NB; ++b)
            *reinterpret_cast<float4*>(&red[(((wave * NB) + b) * LB + lsub) * COUT + og * 4]) = acc[b];
    }
    __syncthreads();

    // ---- combine 4 waves + bias; thread=(b,o) writes float4 over l ----
    const int ob = tid >> 5;
    const int oo = tid & 31;
    float s[LB];
    #pragma unroll
    for (int l = 0; l < LB; ++l)
        s[l] = red[((0 * NB + ob) * LB + l) * COUT + oo]
             + red[((1 * NB + ob) * LB + l) * COUT + oo]
             + red[((2 * NB + ob) * LB + l) * COUT + oo]
             + red[((3 * NB + ob) * LB + l) * COUT + oo];
    const float4 bv = *reinterpret_cast<const float4*>(bias + (size_t)oo * LTOT + l0);
    const float4 o4 = make_float4(s[0] + bv.x, s[1] + bv.y, s[2] + bv.z, s[3] + bv.w);
    *reinterpret_cast<float4*>(out + ((size_t)(ob * COUT + oo)) * LTOT + l0) = o4;
}

extern "C" void kernel_launch(void* const* d_in, const int* in_sizes, int n_in,
                              void* d_out, int out_size, void* d_ws, size_t ws_size,
                              hipStream_t stream) {
    const float* x    = (const float*)d_in[0];
    const float* wgt  = (const float*)d_in[1];
    const float* bias = (const float*)d_in[2];
    float* out        = (float*)d_out;
    lc2d<<<NBLK, 256, 0, stream>>>(x, wgt, bias, out);
}